// Round 14
// baseline (86.319 us; speedup 1.0000x reference)
//
#include <hip/hip_runtime.h>
#include <math.h>

#define L_IN   1048576
#define NBATCH 16
#define T_FR   2049
#define NBINS  513

// ---------------- packed complex: f2 = {re, im}, ops map to v_pk_*_f32 ----------------
typedef __attribute__((ext_vector_type(2))) float f2;

#define RSQ2 0.70710678118654752f
// a * (-i) = {a.y, -a.x}
static __device__ __forceinline__ f2 cnegi(f2 a){ return (f2){a.y, -a.x}; }
// a * w8 = (1-i)/sqrt2 :  RSQ2 * {a.x+a.y, a.y-a.x}
static __device__ __forceinline__ f2 cw8 (f2 a){ f2 t = {a.y, -a.x}; return RSQ2*(a+t); }
// a * w8^3 = RSQ2 * {a.y-a.x, -(a.x+a.y)}
static __device__ __forceinline__ f2 cw83(f2 a){ f2 t = {a.y, -a.x}; return RSQ2*(t-a); }
// full complex multiply: 2 pk ops after fma contraction
static __device__ __forceinline__ f2 cmul(f2 a, f2 b){
  f2 as = {a.x, a.x}, ai = {a.y, a.y}, bs = {-b.y, b.x};
  return as*b + ai*bs;
}

// 8-point DFT, natural order in/out, w8 = e^{-i pi/4}. (verified: impulse at x1 -> y_k = w8^k)
static __device__ __forceinline__ void dft8(const f2 x[8], f2 y[8]) {
  f2 ea0 = x[0]+x[4], ea1 = x[0]-x[4];
  f2 eb0 = x[2]+x[6], eb1 = x[2]-x[6];
  f2 oa0 = x[1]+x[5], oa1 = x[1]-x[5];
  f2 ob0 = x[3]+x[7], ob1 = x[3]-x[7];
  f2 E0 = ea0+eb0, E2 = ea0-eb0;
  f2 nb = cnegi(eb1);
  f2 E1 = ea1+nb,  E3 = ea1-nb;
  f2 O0 = oa0+ob0, O2 = oa0-ob0;
  f2 no = cnegi(ob1);
  f2 O1 = oa1+no,  O3 = oa1-no;
  y[0] = E0+O0;  y[4] = E0-O0;
  f2 t1 = cw8(O1);   y[1] = E1+t1; y[5] = E1-t1;
  f2 t2 = cnegi(O2); y[2] = E2+t2; y[6] = E2-t2;
  f2 t3 = cw83(O3);  y[3] = E3+t3; y[7] = E3-t3;
}

// LDS bank-spread swizzle (bijective on [0,512)) — verified per access pattern in R8.
__device__ __forceinline__ int phys(int idx) { return idx ^ ((idx >> 4) & 15); }

__device__ __forceinline__ unsigned short f2bf(float f) {
  unsigned int u = __builtin_bit_cast(unsigned int, f);
  u += 0x7FFFu + ((u >> 16) & 1u);   // RNE
  return (unsigned short)(u >> 16);
}

#define TWOPI 6.283185307179586f

// raw (unwindowed) frame load; reflect only for edge frames (wave-uniform branch)
__device__ __forceinline__ void load_raw(float2 v[8], const float* __restrict__ xb,
                                         int tt, int t) {
  const int s0 = tt*512 - 512;
  if (tt != 0 && tt != 2048) {
    #pragma unroll
    for (int j = 0; j < 8; ++j) v[j] = *(const float2*)&xb[s0 + 2*(t + 64*j)];
  } else {
    #pragma unroll
    for (int j = 0; j < 8; ++j) {
      int e0 = s0 + 2*(t + 64*j), e1 = e0 + 1;
      int r0 = e0 < 0 ? -e0 : (e0 >= L_IN ? 2*L_IN - 2 - e0 : e0);
      int r1 = e1 < 0 ? -e1 : (e1 >= L_IN ? 2*L_IN - 2 - e1 : e1);
      v[j] = { xb[r0], xb[r1] };
    }
  }
}

// per-frame: window -> radix-8 x3 Stockham (2 LDS exchanges) -> shfl real unpack
// -> bf16 magnitude stage.  FENCE-free (R13-verified): per-wave DS ops are
// serviced in order; compiler inserts counted lgkmcnt before each register use.
// Unpack uses pre-folded V[j] = -0.5*i*W_1024^k:  X = 0.5*A + V*B,
// A = Zk + Zp*{1,-1}, B = Zk - Zp*{1,-1}.  (verified at k=0 and k=512)
__device__ __forceinline__ void process_frame(const float2 v[8], const f2 wl[8],
    const f2 tws1[8], const f2 tws2[8], const f2 vu[8],
    f2* __restrict__ cfw, unsigned short (* __restrict__ mag)[34], int t, int tl)
{
  f2 x[8], y[8];
  #pragma unroll
  for (int j = 0; j < 8; ++j) { f2 raw = {v[j].x, v[j].y}; x[j] = raw * wl[j]; }
  dft8(x, y);                                   // stage 0 (Ls=1)
  #pragma unroll
  for (int k = 0; k < 8; ++k) cfw[phys(8*t + k)] = y[k];
  {                                             // stage 1 (Ls=8): tw = W_64^{m j}
    const int m = t & 7, g = t >> 3;
    f2 xs[8];
    #pragma unroll
    for (int j = 0; j < 8; ++j) xs[j] = cfw[phys(t + 64*j)];
    #pragma unroll
    for (int j = 1; j < 8; ++j) xs[j] = cmul(xs[j], tws1[j]);
    dft8(xs, y);
    #pragma unroll
    for (int k = 0; k < 8; ++k) cfw[phys(g*64 + m + 8*k)] = y[k];
  }
  f2 z[8];
  {                                             // stage 2 (Ls=64): tw = W_512^{t j}
    f2 xs[8];
    #pragma unroll
    for (int j = 0; j < 8; ++j) xs[j] = cfw[phys(t + 64*j)];
    #pragma unroll
    for (int j = 1; j < 8; ++j) xs[j] = cmul(xs[j], tws2[j]);
    dft8(xs, z);                                // z[k] = Z[t + 64k], natural order, regs only
  }
  // real-FFT unpack via cross-lane shuffle: partner Z[(512-k)&511]
  // k=t+64j: t>=1 -> lane 64-t, reg 7-j; t==0 -> lane 0 (self), reg (8-j)&7
  const int pl = (64 - t) & 63;
  #pragma unroll
  for (int j = 0; j < 8; ++j) {
    const int k = t + 64*j;
    f2 Zp = { __shfl(z[7-j].x, pl), __shfl(z[7-j].y, pl) };
    if (t == 0) { f2 s = z[(8-j) & 7]; Zp = s; }
    f2 P  = { Zp.x, -Zp.y };                    // Zp * {1,-1}
    f2 A  = z[j] + P;
    f2 B  = z[j] - P;
    f2 X  = 0.5f*A + cmul(vu[j], B);
    mag[k][tl] = f2bf(sqrtf(X.x*X.x + X.y*X.y));
  }
  if (t == 0) mag[512][tl] = f2bf(fabsf(z[0].x - z[0].y));   // X[512] = ReZ0 - ImZ0
}

// One block = 32 consecutive frames of one batch; 4 waves x 8 frames each.
// (256,3): R10/R12 proved tighter bounds / bigger live sets spill (FETCH canary).
__global__ __launch_bounds__(256, 3)
void stft_fft(const float* __restrict__ input,
              const float* __restrict__ basis,
              float* __restrict__ out)
{
  __shared__ f2 cf[4][512];                 // per-wave exchange array (16 KB)
  __shared__ unsigned short mag[513][34];   // bf16 transpose staging (34.9 KB) -> 51.3 KB

  const int tid = threadIdx.x;
  const int t   = tid & 63;        // lane
  const int w   = tid >> 6;        // wave 0..3

  // ---- XCD swizzle: 1040 = 8 x 130 (bijective); adjacent frame-tiles of one
  // batch land on one XCD -> straddled output lines merge in its L2.
  const int bid  = blockIdx.x;
  const int wg   = (bid & 7) * 130 + (bid >> 3);
  const int b    = wg / 65;               // batch
  const int t0   = (wg - b * 65) << 5;    // first frame of this 32-frame tile

  // ---- per-lane twiddle registers (frame-invariant) ----
  // vu[j] = -0.5*i*W_1024^k = {-0.5*sin(th), -0.5*cos(th)}, th = 2pi k/1024
  f2 tws1[8], tws2[8], vu[8];
  {
    const int m = t & 7;
    #pragma unroll
    for (int j = 1; j < 8; ++j) {
      float s, c, a1 = (TWOPI/64.0f)  * (float)(m*j);
      __sincosf(a1, &s, &c); tws1[j] = { c, -s };
      float a2 = (TWOPI/512.0f) * (float)(t*j);
      __sincosf(a2, &s, &c); tws2[j] = { c, -s };
    }
    #pragma unroll
    for (int j = 0; j < 8; ++j) {
      float s, c, a = (TWOPI/1024.0f) * (float)(t + 64*j);
      __sincosf(a, &s, &c); vu[j] = { -0.5f*s, -0.5f*c };
    }
  }

  // ---- window preload (basis row 0 == hann window, real(fb[0]) == 1) ----
  f2 wl[8];
  #pragma unroll
  for (int j = 0; j < 8; ++j) {
    float2 wv = *(const float2*)&basis[2*(t + 64*j)];
    wl[j] = { wv.x, wv.y };
  }

  const float* xb = input + (size_t)b * L_IN;
  f2* cfw = cf[w];
  const int base = t0 + w*8;
  // clamp (only the t0=2048 tile duplicates frame 2048; final write guards tt)
  const int f0 = base     < 2048 ? base     : 2048;
  const int f1 = base + 1 < 2048 ? base + 1 : 2048;
  const int f2i= base + 2 < 2048 ? base + 2 : 2048;
  const int f3 = base + 3 < 2048 ? base + 3 : 2048;
  const int f4 = base + 4 < 2048 ? base + 4 : 2048;
  const int f5 = base + 5 < 2048 ? base + 5 : 2048;
  const int f6 = base + 6 < 2048 ? base + 6 : 2048;
  const int f7 = base + 7 < 2048 ? base + 7 : 2048;

  // ---- 8 frames per wave, ping-pong prefetch (named buffers: no dyn-idx spill) ----
  float2 va[8], vb[8];
  load_raw(va, xb, f0, t);
  load_raw(vb, xb, f1, t);
  process_frame(va, wl, tws1, tws2, vu, cfw, mag, t, w*8    ); load_raw(va, xb, f2i, t);
  process_frame(vb, wl, tws1, tws2, vu, cfw, mag, t, w*8 + 1); load_raw(vb, xb, f3, t);
  process_frame(va, wl, tws1, tws2, vu, cfw, mag, t, w*8 + 2); load_raw(va, xb, f4, t);
  process_frame(vb, wl, tws1, tws2, vu, cfw, mag, t, w*8 + 3); load_raw(vb, xb, f5, t);
  process_frame(va, wl, tws1, tws2, vu, cfw, mag, t, w*8 + 4); load_raw(va, xb, f6, t);
  process_frame(vb, wl, tws1, tws2, vu, cfw, mag, t, w*8 + 5); load_raw(vb, xb, f7, t);
  process_frame(va, wl, tws1, tws2, vu, cfw, mag, t, w*8 + 6);
  process_frame(vb, wl, tws1, tws2, vu, cfw, mag, t, w*8 + 7);

  __syncthreads();

  // ---- coalesced output: 128 B chunks along t, bf16 -> f32 ----
  const size_t ob = (size_t)b * NBINS * T_FR;
  for (int idx = tid; idx < NBINS*32; idx += 256) {
    const int row = idx >> 5, tl = idx & 31, tt = t0 + tl;
    if (tt <= 2048) {
      unsigned int u = (unsigned int)mag[row][tl] << 16;
      out[ob + (size_t)row * T_FR + tt] = __builtin_bit_cast(float, u);
    }
  }
}

extern "C" void kernel_launch(void* const* d_in, const int* in_sizes, int n_in,
                              void* d_out, int out_size, void* d_ws, size_t ws_size,
                              hipStream_t stream) {
  const float* input = (const float*)d_in[0];
  const float* basis = (const float*)d_in[1];
  float* out = (float*)d_out;
  // 65 frame-tiles of 32 x 16 batches = 1040 blocks, 1-D grid for XCD swizzle
  stft_fft<<<dim3(65 * 16), 256, 0, stream>>>(input, basis, out);
}

// Round 15
// 58.043 us; speedup vs baseline: 1.4871x; 1.4871x over previous
//
#include <hip/hip_runtime.h>
#include <math.h>

#define L_IN   1048576
#define NBATCH 16
#define T_FR   2049
#define NBINS  513

// ---------------- complex helpers (scalar — R14 proved packed f2 regresses) ----------------
struct C2 { float r, i; };
__device__ __forceinline__ C2 cadd(C2 a, C2 b){ return {a.r+b.r, a.i+b.i}; }
__device__ __forceinline__ C2 csub(C2 a, C2 b){ return {a.r-b.r, a.i-b.i}; }
__device__ __forceinline__ C2 cmul(C2 a, C2 b){ return {a.r*b.r - a.i*b.i, a.r*b.i + a.i*b.r}; }
__device__ __forceinline__ C2 cnegi(C2 a){ return {a.i, -a.r}; }            // a * (-i)
#define RSQ2 0.70710678118654752f
__device__ __forceinline__ C2 cw8 (C2 a){ return { RSQ2*(a.r+a.i),  RSQ2*(a.i-a.r)}; }  // a * w8
__device__ __forceinline__ C2 cw83(C2 a){ return { RSQ2*(a.i-a.r), -RSQ2*(a.r+a.i)}; }  // a * w8^3

// 8-point DFT, natural order in/out, w8 = e^{-i pi/4}. (verified: impulse at x1 -> y_k = w8^k)
__device__ __forceinline__ void dft8(const C2 x[8], C2 y[8]) {
  C2 ea0 = cadd(x[0], x[4]), ea1 = csub(x[0], x[4]);
  C2 eb0 = cadd(x[2], x[6]), eb1 = csub(x[2], x[6]);
  C2 oa0 = cadd(x[1], x[5]), oa1 = csub(x[1], x[5]);
  C2 ob0 = cadd(x[3], x[7]), ob1 = csub(x[3], x[7]);
  C2 E0 = cadd(ea0, eb0), E2 = csub(ea0, eb0);
  C2 nb = cnegi(eb1);
  C2 E1 = cadd(ea1, nb),  E3 = csub(ea1, nb);
  C2 O0 = cadd(oa0, ob0), O2 = csub(oa0, ob0);
  C2 no = cnegi(ob1);
  C2 O1 = cadd(oa1, no),  O3 = csub(oa1, no);
  y[0] = cadd(E0, O0);  y[4] = csub(E0, O0);
  C2 t1 = cw8(O1);      y[1] = cadd(E1, t1); y[5] = csub(E1, t1);
  C2 t2 = cnegi(O2);    y[2] = cadd(E2, t2); y[6] = csub(E2, t2);
  C2 t3 = cw83(O3);     y[3] = cadd(E3, t3); y[7] = csub(E3, t3);
}

// LDS bank-spread swizzle (bijective on [0,512)) — verified per access pattern in R8.
__device__ __forceinline__ int phys(int idx) { return idx ^ ((idx >> 4) & 15); }

__device__ __forceinline__ unsigned short f2bf(float f) {
  unsigned int u = __builtin_bit_cast(unsigned int, f);
  u += 0x7FFFu + ((u >> 16) & 1u);   // RNE
  return (unsigned short)(u >> 16);
}

#define TWOPI 6.283185307179586f

// raw (unwindowed) frame load; reflect only for edge frames (wave-uniform branch)
__device__ __forceinline__ void load_raw(float2 v[8], const float* __restrict__ xb,
                                         int tt, int t) {
  const int s0 = tt*512 - 512;
  if (tt != 0 && tt != 2048) {
    #pragma unroll
    for (int j = 0; j < 8; ++j) v[j] = *(const float2*)&xb[s0 + 2*(t + 64*j)];
  } else {
    #pragma unroll
    for (int j = 0; j < 8; ++j) {
      int e0 = s0 + 2*(t + 64*j), e1 = e0 + 1;
      int r0 = e0 < 0 ? -e0 : (e0 >= L_IN ? 2*L_IN - 2 - e0 : e0);
      int r1 = e1 < 0 ? -e1 : (e1 >= L_IN ? 2*L_IN - 2 - e1 : e1);
      v[j] = { xb[r0], xb[r1] };
    }
  }
}

// ---- pipeline stages (FENCE-free: per-wave DS ops in order + may-alias pinning,
// validated by R13's pass). Splitting into stages lets two frames interleave. ----
__device__ __forceinline__ void stage0(const float2 v[8], const float2 wl[8],
                                       C2* __restrict__ cfh, int t) {
  C2 x[8], y[8];
  #pragma unroll
  for (int j = 0; j < 8; ++j) x[j] = { v[j].x * wl[j].x, v[j].y * wl[j].y };
  dft8(x, y);
  #pragma unroll
  for (int k = 0; k < 8; ++k) cfh[phys(8*t + k)] = y[k];
}

__device__ __forceinline__ void stage1(C2* __restrict__ cfh, const C2 tws1[8], int t) {
  const int m = t & 7, g = t >> 3;
  C2 xs[8], y[8];
  #pragma unroll
  for (int j = 0; j < 8; ++j) xs[j] = cfh[phys(t + 64*j)];
  #pragma unroll
  for (int j = 1; j < 8; ++j) xs[j] = cmul(xs[j], tws1[j]);
  dft8(xs, y);
  #pragma unroll
  for (int k = 0; k < 8; ++k) cfh[phys(g*64 + m + 8*k)] = y[k];
}

__device__ __forceinline__ void stage2(C2* __restrict__ cfh, const C2 tws2[8], int t, C2 z[8]) {
  C2 xs[8];
  #pragma unroll
  for (int j = 0; j < 8; ++j) xs[j] = cfh[phys(t + 64*j)];
  #pragma unroll
  for (int j = 1; j < 8; ++j) xs[j] = cmul(xs[j], tws2[j]);
  dft8(xs, z);                                 // z[k] = Z[t + 64k], natural order, regs only
}

// real-FFT unpack via cross-lane shuffle: partner Z[(512-k)&511]
// k=t+64j: t>=1 -> lane 64-t, reg 7-j; t==0 -> lane 0 (self), reg (8-j)&7
__device__ __forceinline__ void unpack(const C2 z[8], const C2 twu[8],
                                       unsigned short (* __restrict__ mag)[18],
                                       int t, int tl) {
  const int pl = (64 - t) & 63;
  #pragma unroll
  for (int j = 0; j < 8; ++j) {
    const int k = t + 64*j;
    C2 Zp = { __shfl(z[7-j].r, pl), __shfl(z[7-j].i, pl) };
    if (t == 0) Zp = z[(8-j) & 7];
    C2 Zk = z[j];
    C2 W  = twu[j];
    float Are = 0.5f*(Zk.r + Zp.r), Aim = 0.5f*(Zk.i - Zp.i);
    float Bre = 0.5f*(Zk.r - Zp.r), Bim = 0.5f*(Zk.i + Zp.i);
    float Xr = Are + (W.r*Bim + W.i*Bre);
    float Xi = Aim - (W.r*Bre - W.i*Bim);
    mag[k][tl] = f2bf(sqrtf(Xr*Xr + Xi*Xi));
  }
  if (t == 0) mag[512][tl] = f2bf(fabsf(z[0].r - z[0].i));   // X[512] = ReZ0 - ImZ0
}

// One block = 16 consecutive frames of one batch; 4 waves x 2 stage-interleaved
// frame-pairs. Frame A's LDS latency hides under frame B's dft8 VALU and vice
// versa; only ONE frame's work registers live at a time (other frame's state is
// in its LDS half) — the minimal-live-set fix for R12's spill.
__global__ __launch_bounds__(256, 3)
void stft_fft(const float* __restrict__ input,
              const float* __restrict__ basis,
              float* __restrict__ out)
{
  __shared__ C2 cf[4][2][512];              // per-wave dual exchange arrays (32 KB)
  __shared__ unsigned short mag[513][18];   // bf16 transpose staging (18.5 KB) -> 50.5 KB

  const int tid = threadIdx.x;
  const int t   = tid & 63;        // lane
  const int w   = tid >> 6;        // wave 0..3

  // ---- XCD swizzle: 2064 = 8 x 258 (bijective); adjacent frame-tiles of one
  // batch land on one XCD -> output-line straddles merge in its L2.
  const int bid = blockIdx.x;
  const int wg  = (bid & 7) * 258 + (bid >> 3);
  const int b   = wg / 129;              // batch
  const int t0  = (wg - b * 129) << 4;   // first frame of this 16-frame tile

  // ---- per-lane twiddle registers (frame-invariant) ----
  C2 tws1[8], tws2[8], twu[8];
  {
    const int m = t & 7;
    #pragma unroll
    for (int j = 1; j < 8; ++j) {
      float s, c, a1 = (TWOPI/64.0f)  * (float)(m*j);
      __sincosf(a1, &s, &c); tws1[j] = { c, -s };
      float a2 = (TWOPI/512.0f) * (float)(t*j);
      __sincosf(a2, &s, &c); tws2[j] = { c, -s };
    }
    #pragma unroll
    for (int j = 0; j < 8; ++j) {
      float s, c, a = (TWOPI/1024.0f) * (float)(t + 64*j);
      __sincosf(a, &s, &c); twu[j] = { c, -s };
    }
  }

  // ---- window preload (basis row 0 == hann window, real(fb[0]) == 1) ----
  float2 wl[8];
  #pragma unroll
  for (int j = 0; j < 8; ++j) wl[j] = *(const float2*)&basis[2*(t + 64*j)];

  const float* xb = input + (size_t)b * L_IN;
  C2* cfA = cf[w][0];
  C2* cfB = cf[w][1];
  const int base = t0 + w*4;
  // clamp tail (only the t0=2048 tile duplicates frame 2048; write guard skips)
  const int f0 = base     < 2048 ? base     : 2048;
  const int f1 = base + 1 < 2048 ? base + 1 : 2048;
  const int f2 = base + 2 < 2048 ? base + 2 : 2048;
  const int f3 = base + 3 < 2048 ? base + 3 : 2048;

  float2 va[8], vb[8];
  C2 z[8];

  // ---- pair 1 (frames f0, f1), stage-interleaved ----
  load_raw(va, xb, f0, t);
  load_raw(vb, xb, f1, t);
  stage0(va, wl, cfA, t);
  load_raw(va, xb, f2, t);          // prefetch pair-2 A under pair-1 compute
  stage0(vb, wl, cfB, t);
  load_raw(vb, xb, f3, t);          // prefetch pair-2 B
  stage1(cfA, tws1, t);
  stage1(cfB, tws1, t);
  stage2(cfA, tws2, t, z);  unpack(z, twu, mag, t, w*4    );
  stage2(cfB, tws2, t, z);  unpack(z, twu, mag, t, w*4 + 1);

  // ---- pair 2 (frames f2, f3) ----
  stage0(va, wl, cfA, t);
  stage0(vb, wl, cfB, t);
  stage1(cfA, tws1, t);
  stage1(cfB, tws1, t);
  stage2(cfA, tws2, t, z);  unpack(z, twu, mag, t, w*4 + 2);
  stage2(cfB, tws2, t, z);  unpack(z, twu, mag, t, w*4 + 3);

  __syncthreads();

  // ---- coalesced output: 64 B chunks along t, bf16 -> f32 ----
  const size_t ob = (size_t)b * NBINS * T_FR;
  for (int idx = tid; idx < NBINS*16; idx += 256) {
    const int row = idx >> 4, tl = idx & 15, tt = t0 + tl;
    if (tt <= 2048) {
      unsigned int u = (unsigned int)mag[row][tl] << 16;
      out[ob + (size_t)row * T_FR + tt] = __builtin_bit_cast(float, u);
    }
  }
}

extern "C" void kernel_launch(void* const* d_in, const int* in_sizes, int n_in,
                              void* d_out, int out_size, void* d_ws, size_t ws_size,
                              hipStream_t stream) {
  const float* input = (const float*)d_in[0];
  const float* basis = (const float*)d_in[1];
  float* out = (float*)d_out;
  // 129 frame-tiles of 16 x 16 batches = 2064 blocks, 1-D grid for XCD swizzle
  stft_fft<<<dim3(129 * 16), 256, 0, stream>>>(input, basis, out);
}